// Round 17
// baseline (328.172 us; speedup 1.0000x reference)
//
#include <hip/hip_runtime.h>
#include <hip/hip_bf16.h>

// ---------------------------------------------------------------------------
// R17: TWO-PASS attention stats with 512x512 2-D tiles (traffic, not plumbing).
// R12-R16 evidence: k_col time ∝ bytes streamed (~6-7 TB/s ceiling) across
// every memory strategy; single-pass W-acc registers capped tile width at 64
// -> 256MB traffic. Two-pass accumulators are scalars (Z[j], s[i]) -> 512-wide
// tiles -> 33MB/pass. exp is recomputed (2x67M) but the exp pipe is ~1.7us.
//   k_front: conv+proj -> fragment-order prF/pdF (pvF DROPPED) + rgbd + ctr=0
//   k_z:     grid 256 = 4b x 8jc x 8ic; Z partials (zacc[32] static regs)
//   k_s:     same grid; s partials over jc; phase-2 folds gap contribution
//            (exact: gap = sum_jc sum_i s_partial*v); last-block MLP gate.
// Math validated R3-R7 (two-pass) + R11 (fragment layouts): absmax 0.0039.
// ---------------------------------------------------------------------------

typedef __bf16 bf16;
typedef __bf16 bf16x4 __attribute__((ext_vector_type(4)));
typedef __bf16 bf16x8 __attribute__((ext_vector_type(8)));
typedef float  f32x4  __attribute__((ext_vector_type(4)));
typedef float  float4v __attribute__((ext_vector_type(4)));
typedef int    i32x4  __attribute__((ext_vector_type(4)));

#define MFMA_BF16(a, b, c) __builtin_amdgcn_mfma_f32_16x16x32_bf16((a), (b), (c), 0, 0, 0)

#if defined(__has_builtin)
# if __has_builtin(__builtin_amdgcn_exp2f)
#  define EXP2(x) __builtin_amdgcn_exp2f(x)
# else
#  define EXP2(x) exp2f(x)
# endif
#else
# define EXP2(x) exp2f(x)
#endif

#define K_E 0.18033688f      // 0.125 * log2(e)
#define K_EINV 5.5451774f    // 1 / K_E

__device__ __forceinline__ int swz128(int row, int colByte) {
    return row * 128 + (colByte ^ ((row & 7) << 4));
}
__device__ __forceinline__ int swz512(int row, int colByte) {
    return row * 512 + (colByte ^ ((row & 15) << 4));
}

// LDS union offsets for K_A
#define OW_W   0
#define OW_WR  32768
#define OW_WD  40960
#define OT_C   0
#define OT_R   16384
#define OT_D   20480
#define O_S1   49152
#define O_B1   49408
#define O_RED  49664
#define SMEMA  51712

// ---------------------------------------------------------------------------
// K_A: self-staged weights -> conv+BN+ReLU -> proj -> fragment-order stores.
// prF/pdF: f(i,c) = (i>>4)*1024 + (c>>3)*128 + (i&15)*8 + (c&7)   (per batch)
// ---------------------------------------------------------------------------
__global__ __launch_bounds__(512, 2) void k_front(
    const float* __restrict__ rgb, const float* __restrict__ dep,
    const float* __restrict__ conv_w,
    const float* __restrict__ bn1_g, const float* __restrict__ bn1_b,
    const float* __restrict__ bn1_m, const float* __restrict__ bn1_v,
    const float* __restrict__ rgb_w, const float* __restrict__ dep_w,
    bf16* __restrict__ prF, bf16* __restrict__ pdF,
    float* __restrict__ rgbdPart, int* __restrict__ counter)
{
    const int bid = blockIdx.x;
    const int xcd = bid & 7;
    const int b    = xcd >> 1;
    const int tile = ((bid >> 3) << 1) | (xcd & 1);
    const int p0   = tile * 32;
    const int tid = threadIdx.x;
    const int w   = tid >> 6;
    const int lane = tid & 63;
    const int l15 = lane & 15;
    const int lg  = lane >> 4;
    const int ot4 = w & 3;
    const int ot  = ot4 * 16;
    const int ph  = w >> 2;

    if (bid == 0 && tid == 0) *counter = 0;

    __shared__ __align__(16) unsigned char smem[SMEMA];
    float* s1 = (float*)(smem + O_S1);
    float* b1 = (float*)(smem + O_B1);
    float* red = (float*)(smem + O_RED);

    // ---- phase W: stage all weights coalesced -> swizzled LDS bf16 ----
    {
        unsigned char* ldsW  = smem + OW_W;
        unsigned char* ldsWR = smem + OW_WR;
        unsigned char* ldsWD = smem + OW_WD;
        #pragma unroll
        for (int q = 0; q < 8; ++q) {
            const int idx = (q * 512 + tid) * 4;
            float4v v = *(const float4v*)(conv_w + idx);
            const int o = idx >> 8, c = idx & 255;
            bf16x4 h;
            #pragma unroll
            for (int j = 0; j < 4; ++j) h[j] = (bf16)v[j];
            *(bf16x4*)(ldsW + swz512(o, c * 2)) = h;
        }
        #pragma unroll
        for (int q = 0; q < 2; ++q) {
            const int idx = (q * 512 + tid) * 4;
            const int o = idx >> 6, c = idx & 63;
            float4v v = *(const float4v*)(rgb_w + idx);
            bf16x4 h;
            #pragma unroll
            for (int j = 0; j < 4; ++j) h[j] = (bf16)v[j];
            *(bf16x4*)(ldsWR + swz128(o, c * 2)) = h;
            v = *(const float4v*)(dep_w + idx);
            #pragma unroll
            for (int j = 0; j < 4; ++j) h[j] = (bf16)v[j];
            *(bf16x4*)(ldsWD + swz128(o, c * 2)) = h;
        }
        if (tid < 64) {
            float sc = bn1_g[tid] * rsqrtf(bn1_v[tid] + 1e-5f);
            s1[tid] = sc;
            b1[tid] = bn1_b[tid] - bn1_m[tid] * sc;
        }
    }
    __syncthreads();

    // ---- fragments -> registers ----
    bf16x8 aW[8], aR[2], aD[2];
    {
        const unsigned char* ldsW  = smem + OW_W;
        const unsigned char* ldsWR = smem + OW_WR;
        const unsigned char* ldsWD = smem + OW_WD;
        const int row = ot + l15;
        #pragma unroll
        for (int kk = 0; kk < 8; ++kk)
            aW[kk] = *(const bf16x8*)(ldsW + swz512(row, (kk * 32 + lg * 8) * 2));
        #pragma unroll
        for (int kk = 0; kk < 2; ++kk) {
            aR[kk] = *(const bf16x8*)(ldsWR + swz128(row, (kk * 32 + lg * 8) * 2));
            aD[kk] = *(const bf16x8*)(ldsWD + swz128(row, (kk * 32 + lg * 8) * 2));
        }
    }
    __syncthreads();

    // ---- phase T: stage dep/rgb tiles coalesced ----
    unsigned char* ldsC = smem + OT_C;
    unsigned char* ldsR = smem + OT_R;
    unsigned char* ldsD = smem + OT_D;
    const float* depb = dep + (size_t)b * 256 * 4096;
    const float* rgbb = rgb + (size_t)b * 64 * 4096;
    {
        const int c0 = tid >> 3, seg = tid & 7;
        #pragma unroll
        for (int r = 0; r < 4; ++r) {
            const int c = r * 64 + c0;
            float4v v = *(const float4v*)(depb + (size_t)c * 4096 + p0 + seg * 4);
            #pragma unroll
            for (int k = 0; k < 4; ++k)
                *(bf16*)(ldsC + swz512(seg * 4 + k, c * 2)) = (bf16)v[k];
        }
        float4v v = *(const float4v*)(rgbb + (size_t)c0 * 4096 + p0 + seg * 4);
        #pragma unroll
        for (int k = 0; k < 4; ++k)
            *(bf16*)(ldsR + swz128(seg * 4 + k, c0 * 2)) = (bf16)v[k];
    }
    __syncthreads();

    // ---- conv MFMA K=256 ----
    const int prow = ph * 16 + l15;
    f32x4 acc = {0.f, 0.f, 0.f, 0.f};
    #pragma unroll
    for (int kk = 0; kk < 8; ++kk) {
        bf16x8 bF = *(const bf16x8*)(ldsC + swz512(prow, (kk * 32 + lg * 8) * 2));
        acc = MFMA_BF16(aW[kk], bF, acc);
    }
    {
        const int o0 = ot + lg * 4;
        bf16x4 v4;
        #pragma unroll
        for (int r = 0; r < 4; ++r) {
            float x = acc[r] * s1[o0 + r] + b1[o0 + r];
            v4[r] = (bf16)(x > 0.f ? x : 0.f);
        }
        *(bf16x4*)(ldsD + swz128(prow, o0 * 2)) = v4;
    }
    __syncthreads();

    // ---- proj GEMMs (K=64) + fragment-order stores ----
    f32x4 accR = {0.f, 0.f, 0.f, 0.f}, accD = {0.f, 0.f, 0.f, 0.f};
    #pragma unroll
    for (int kk = 0; kk < 2; ++kk) {
        const int cb = (kk * 32 + lg * 8) * 2;
        bf16x8 bR = *(const bf16x8*)(ldsR + swz128(prow, cb));
        bf16x8 bD = *(const bf16x8*)(ldsD + swz128(prow, cb));
        accR = MFMA_BF16(aR[kk], bR, accR);
        accD = MFMA_BF16(aD[kk], bD, accD);
    }
    {
        const int o0 = ot + lg * 4;
        const size_t itile = (size_t)tile * 2 + ph;
        const size_t fbase = (size_t)b * 262144 + itile * 1024;
        const size_t prOff = fbase + (size_t)(o0 >> 3) * 128 + l15 * 8 + (o0 & 7);
        bf16x4 vR, vD;
        #pragma unroll
        for (int r = 0; r < 4; ++r) {
            vR[r] = (bf16)(accR[r] * K_E);
            vD[r] = (bf16)accD[r];
        }
        *(bf16x4*)(prF + prOff) = vR;
        *(bf16x4*)(pdF + prOff) = vD;
    }

    // ---- rgbd per-tile sums ----
    {
        const int c = tid & 63, g8 = tid >> 6;
        float sum = 0.f;
        #pragma unroll
        for (int q = 0; q < 4; ++q) {
            const int pp = g8 * 4 + q;
            sum += (float)*(const bf16*)(ldsR + swz128(pp, c * 2))
                 + (float)*(const bf16*)(ldsD + swz128(pp, c * 2));
        }
        red[g8 * 64 + c] = sum;
    }
    __syncthreads();
    if (tid < 64) {
        float s = 0.f;
        #pragma unroll
        for (int g = 0; g < 8; ++g) s += red[g * 64 + tid];
        rgbdPart[((size_t)b * 128 + tile) * 64 + tid] = s;
    }
}

// ---------------------------------------------------------------------------
// K_Z: Z partials over 512x512 tiles. Grid 256 = b(4) x jc(8) x ic(8),
// 512 thr. pd j-chunk (64KB) staged to LDS once; pr A-frags resident
// (4 i-tiles/wave); zacc[32] static registers; epilogue reduces to
// Zpart[ic][b][4096].
// ---------------------------------------------------------------------------
__global__ __launch_bounds__(512, 4) void k_z(
    const bf16* __restrict__ prF, const bf16* __restrict__ pdF,
    float* __restrict__ Zpart)
{
    const int bid = blockIdx.x;
    const int b = bid >> 6, rest = bid & 63;
    const int jc = rest >> 3, ic = rest & 7;
    const int tid = threadIdx.x, w = tid >> 6, lane = tid & 63;

    __shared__ __align__(16) bf16 pdL[32768];   // 64KB j-chunk

    const bf16* prb = prF + (size_t)b * 262144;
    const bf16* pdb = pdF + (size_t)b * 262144;

    // stage pd j-chunk (fragment order is contiguous per chunk)
    {
        const i32x4* src = (const i32x4*)(pdb + (size_t)jc * 32768);
        i32x4* dst = (i32x4*)pdL;
        #pragma unroll
        for (int q = 0; q < 8; ++q)
            dst[q * 512 + tid] = src[q * 512 + tid];
    }
    // resident A-frags: 4 i-tiles per wave
    bf16x8 A0[4], A1[4];
    #pragma unroll
    for (int it = 0; it < 4; ++it) {
        const bf16* p = prb + (size_t)(ic * 32 + w * 4 + it) * 1024 + lane * 8;
        A0[it] = *(const bf16x8*)p;
        A1[it] = *(const bf16x8*)(p + 512);
    }
    __syncthreads();

    float zacc[32];
    #pragma unroll
    for (int jt = 0; jt < 32; ++jt) zacc[jt] = 0.f;

    #pragma unroll
    for (int jt = 0; jt < 32; ++jt) {
        bf16x8 B0 = *(const bf16x8*)(pdL + jt * 1024 + lane * 8);
        bf16x8 B1 = *(const bf16x8*)(pdL + jt * 1024 + 512 + lane * 8);
        #pragma unroll
        for (int it = 0; it < 4; ++it) {
            f32x4 e = {0.f, 0.f, 0.f, 0.f};
            e = MFMA_BF16(A0[it], B0, e);
            e = MFMA_BF16(A1[it], B1, e);
            zacc[jt] += (EXP2(e[0]) + EXP2(e[1])) + (EXP2(e[2]) + EXP2(e[3]));
        }
    }
    __syncthreads();            // pdL fully consumed; reuse as zred
    float* zred = (float*)pdL;  // [8][512]
    #pragma unroll
    for (int jt = 0; jt < 32; ++jt) {
        float v = zacc[jt];
        v += __shfl_xor(v, 16);
        v += __shfl_xor(v, 32);
        if (lane < 16) zred[w * 512 + jt * 16 + lane] = v;
    }
    __syncthreads();
    {
        float s = 0.f;
        #pragma unroll
        for (int k = 0; k < 8; ++k) s += zred[k * 512 + tid];
        Zpart[((size_t)ic * 4 + b) * 4096 + jc * 512 + tid] = s;
    }
}

// ---------------------------------------------------------------------------
// K_S: s partials over 512x512 tiles + fused gap contribution + gate.
// Grid 256 = b(4) x jc(8) x ic(8), 512 thr.
//  phase 0: stage pdL; zinv[512] from 8 Zpart slices
//  phase 1: sacc[it][r] += exp2(e)*zinv_j over 32 j-tiles -> s_lds[512]
//  phase 2: gap partial = sum_i s_i * (K_EINV*pr_e + pd)  (resident A + pd)
//  last-block-done (ticket): 4-batch MLP gate.
// ---------------------------------------------------------------------------
__global__ __launch_bounds__(512, 4) void k_s(
    const bf16* __restrict__ prF, const bf16* __restrict__ pdF,
    const float* __restrict__ Zpart,
    float* __restrict__ gapPart, const float* __restrict__ rgbdPart,
    int* __restrict__ counter,
    const float* __restrict__ mlp1_w,
    const float* __restrict__ bn2_g, const float* __restrict__ bn2_b,
    const float* __restrict__ bn2_m, const float* __restrict__ bn2_v,
    const float* __restrict__ mlp2_w,
    const float* __restrict__ bn3_g, const float* __restrict__ bn3_b,
    const float* __restrict__ bn3_m, const float* __restrict__ bn3_v,
    float* __restrict__ out)
{
    const int bid = blockIdx.x;
    const int b = bid >> 6, rest = bid & 63;
    const int jc = rest >> 3, ic = rest & 7;
    const int tid = threadIdx.x, w = tid >> 6, lane = tid & 63;
    const int l15 = lane & 15, lg = lane >> 4;

    __shared__ __align__(16) bf16 pdL[32768];   // 64KB
    __shared__ float zinv_lds[512];
    __shared__ float s_lds[512];
    __shared__ float gred[8][64];
    __shared__ float gv4[4][64];
    __shared__ float h4[4][24];
    __shared__ int winflag;
    if (tid == 0) winflag = 0;

    const bf16* prb = prF + (size_t)b * 262144;
    const bf16* pdb = pdF + (size_t)b * 262144;

    // stage pd j-chunk
    {
        const i32x4* src = (const i32x4*)(pdb + (size_t)jc * 32768);
        i32x4* dst = (i32x4*)pdL;
        #pragma unroll
        for (int q = 0; q < 8; ++q)
            dst[q * 512 + tid] = src[q * 512 + tid];
    }
    // zinv prologue: thread t -> j = jc*512 + t
    {
        const float* zp = Zpart + (size_t)b * 4096 + jc * 512 + tid;
        float s = 0.f;
        #pragma unroll
        for (int k = 0; k < 8; ++k) s += zp[(size_t)k * 16384];
        float zi = __builtin_amdgcn_rcpf(s);
        zinv_lds[tid] = zi * (2.0f - s * zi);
    }
    // resident A-frags
    bf16x8 A0[4], A1[4];
    #pragma unroll
    for (int it = 0; it < 4; ++it) {
        const bf16* p = prb + (size_t)(ic * 32 + w * 4 + it) * 1024 + lane * 8;
        A0[it] = *(const bf16x8*)p;
        A1[it] = *(const bf16x8*)(p + 512);
    }
    __syncthreads();

    float sacc[4][4] = {};
    #pragma unroll
    for (int jt = 0; jt < 32; ++jt) {
        bf16x8 B0 = *(const bf16x8*)(pdL + jt * 1024 + lane * 8);
        bf16x8 B1 = *(const bf16x8*)(pdL + jt * 1024 + 512 + lane * 8);
        const float zv = zinv_lds[jt * 16 + l15];
        #pragma unroll
        for (int it = 0; it < 4; ++it) {
            f32x4 e = {0.f, 0.f, 0.f, 0.f};
            e = MFMA_BF16(A0[it], B0, e);
            e = MFMA_BF16(A1[it], B1, e);
            sacc[it][0] += EXP2(e[0]) * zv;
            sacc[it][1] += EXP2(e[1]) * zv;
            sacc[it][2] += EXP2(e[2]) * zv;
            sacc[it][3] += EXP2(e[3]) * zv;
        }
    }
    // phase-1 epilogue: s per row -> s_lds
    #pragma unroll
    for (int it = 0; it < 4; ++it) {
        #pragma unroll
        for (int r = 0; r < 4; ++r) {
            float v = sacc[it][r];
            v += __shfl_xor(v, 1);
            v += __shfl_xor(v, 2);
            v += __shfl_xor(v, 4);
            v += __shfl_xor(v, 8);
            if (l15 == 0) s_lds[w * 64 + it * 16 + lg * 4 + r] = v;
        }
    }
    __syncthreads();

    // phase 2: gap partial = sum_i s_i * (K_EINV*pr_e[i,c] + pd[i,c])
    float g0[8] = {}, g1[8] = {};
    #pragma unroll
    for (int it = 0; it < 4; ++it) {
        const bf16* p = pdb + (size_t)(ic * 32 + w * 4 + it) * 1024 + lane * 8;
        bf16x8 PD0 = *(const bf16x8*)p;
        bf16x8 PD1 = *(const bf16x8*)(p + 512);
        const float sv = s_lds[w * 64 + it * 16 + l15];
        #pragma unroll
        for (int k = 0; k < 8; ++k) {
            g0[k] += sv * (K_EINV * (float)A0[it][k] + (float)PD0[k]);
            g1[k] += sv * (K_EINV * (float)A1[it][k] + (float)PD1[k]);
        }
    }
    #pragma unroll
    for (int k = 0; k < 8; ++k) {
        float v0 = g0[k], v1 = g1[k];
        v0 += __shfl_xor(v0, 1);
        v0 += __shfl_xor(v0, 2);
        v0 += __shfl_xor(v0, 4);
        v0 += __shfl_xor(v0, 8);
        v1 += __shfl_xor(v1, 1);
        v1 += __shfl_xor(v1, 2);
        v1 += __shfl_xor(v1, 4);
        v1 += __shfl_xor(v1, 8);
        if (l15 == 0) {
            gred[w][lg * 8 + k] = v0;
            gred[w][32 + lg * 8 + k] = v1;
        }
    }
    __syncthreads();
    if (tid < 64) {
        float s = 0.f;
        #pragma unroll
        for (int k = 0; k < 8; ++k) s += gred[k][tid];
        gapPart[((size_t)b * 64 + jc * 8 + ic) * 64 + tid] = s;
        __threadfence();
        int old = atomicAdd(counter, 1);
        if (old == 256 * 64 - 1) winflag = 1;
    }
    __syncthreads();

    // ================= last block: MLP gate ==================
    if (winflag) {
        __threadfence();
        const int wb = w >> 1, half = w & 1;
        float acc2 = 0.f;
        const float* gp = gapPart + ((size_t)wb * 64 + half * 32) * 64 + lane;
        #pragma unroll 4
        for (int r = 0; r < 32; ++r) acc2 += gp[r * 64];
        const float* rp = rgbdPart + ((size_t)wb * 128 + half * 64) * 64 + lane;
        #pragma unroll 4
        for (int r = 0; r < 64; ++r) acc2 += rp[r * 64];
        gred[w][lane] = acc2;
        __syncthreads();
        if (tid < 256) {
            const int b4 = tid >> 6, c = tid & 63;
            gv4[b4][c] = (gred[2 * b4][c] + gred[2 * b4 + 1][c]) * (1.f / 4096.f);
        }
        __syncthreads();
        if (tid < 96) {
            const int b4 = tid / 24, o = tid % 24;
            float a = 0.f;
            #pragma unroll
            for (int cc = 0; cc < 64; ++cc) a += mlp1_w[o * 64 + cc] * gv4[b4][cc];
            float sc = bn2_g[o] * rsqrtf(bn2_v[o] + 1e-5f);
            a = a * sc + bn2_b[o] - bn2_m[o] * sc;
            h4[b4][o] = a > 0.f ? a : 0.f;
        }
        __syncthreads();
        if (tid < 256) {
            const int b4 = tid >> 6, c = tid & 63;
            float u = 0.f;
            #pragma unroll
            for (int o = 0; o < 24; ++o) u += mlp2_w[c * 24 + o] * h4[b4][o];
            float sc = bn3_g[c] * rsqrtf(bn3_v[c] + 1e-5f);
            u = u * sc + bn3_b[c] - bn3_m[c] * sc;
            out[b4 * 64 + c] = 1.f / (1.f + __expf(-u));
        }
    }
}

// ---------------------------------------------------------------------------
extern "C" void kernel_launch(void* const* d_in, const int* in_sizes, int n_in,
                              void* d_out, int out_size, void* d_ws, size_t ws_size,
                              hipStream_t stream)
{
    const float* rgb    = (const float*)d_in[0];
    const float* dep    = (const float*)d_in[1];
    const float* conv_w = (const float*)d_in[2];
    const float* bn1_g  = (const float*)d_in[3];
    const float* bn1_b  = (const float*)d_in[4];
    const float* bn1_m  = (const float*)d_in[5];
    const float* bn1_v  = (const float*)d_in[6];
    const float* rgb_w  = (const float*)d_in[7];
    const float* dep_w  = (const float*)d_in[8];
    const float* mlp1_w = (const float*)d_in[9];
    const float* bn2_g  = (const float*)d_in[10];
    const float* bn2_b  = (const float*)d_in[11];
    const float* bn2_m  = (const float*)d_in[12];
    const float* bn2_v  = (const float*)d_in[13];
    const float* mlp2_w = (const float*)d_in[14];
    const float* bn3_g  = (const float*)d_in[15];
    const float* bn3_b  = (const float*)d_in[16];
    const float* bn3_m  = (const float*)d_in[17];
    const float* bn3_v  = (const float*)d_in[18];

    char* ws = (char*)d_ws;
    bf16*  prF      = (bf16*)(ws);                                  // 2 MB
    bf16*  pdF      = (bf16*)(ws + (2u << 20));                     // 2 MB
    float* Zpart    = (float*)(ws + (4u << 20));                    // 512 KB
    float* rgbdPart = (float*)(ws + (4u << 20) + (512u << 10));     // 128 KB
    float* gapPart  = (float*)(ws + (4u << 20) + (640u << 10));     // 64 KB
    int*   counter  = (int*)  (ws + (4u << 20) + (704u << 10));     // 4 B

    k_front<<<512, 512, 0, stream>>>(rgb, dep, conv_w,
                                     bn1_g, bn1_b, bn1_m, bn1_v,
                                     rgb_w, dep_w,
                                     prF, pdF, rgbdPart, counter);
    k_z<<<256, 512, 0, stream>>>(prF, pdF, Zpart);
    k_s<<<256, 512, 0, stream>>>(prF, pdF, Zpart, gapPart, rgbdPart, counter,
                                 mlp1_w, bn2_g, bn2_b, bn2_m, bn2_v,
                                 mlp2_w, bn3_g, bn3_b, bn3_m, bn3_v,
                                 (float*)d_out);
}

// Round 18
// 210.542 us; speedup vs baseline: 1.5587x; 1.5587x over previous
//
#include <hip/hip_runtime.h>
#include <hip/hip_bf16.h>

// ---------------------------------------------------------------------------
// R18: R17 (two-pass, 512x512 tiles, 33MB/pass) with the SPILL FIX.
// R13/R15/R17 evidence: HIP __launch_bounds__ 2nd arg = min BLOCKS per CU
// (CUDA semantics): lb(512,4) -> 32 waves/CU -> 64-VGPR cap -> ~100-reg
// kernels spill (R17: 478MB FETCH + 263MB WRITE scratch, 328us).
// Fix: lb(512,2) on k_z/k_s -> 128-reg cap; LDS (64-73KB) already limits to
// 2 blk/CU so zero occupancy lost.
//   k_front: conv+proj -> fragment-order prF/pdF + rgbd partials + ctr=0
//   k_z:     grid 256 = 4b x 8jc x 8ic; Z partials (zacc[32] static regs)
//   k_s:     same grid; s partials; phase-2 folds gap; last-block MLP gate.
// Math validated R3-R7 (two-pass) + R11 (fragment layouts): absmax 0.0039.
// ---------------------------------------------------------------------------

typedef __bf16 bf16;
typedef __bf16 bf16x4 __attribute__((ext_vector_type(4)));
typedef __bf16 bf16x8 __attribute__((ext_vector_type(8)));
typedef float  f32x4  __attribute__((ext_vector_type(4)));
typedef float  float4v __attribute__((ext_vector_type(4)));
typedef int    i32x4  __attribute__((ext_vector_type(4)));

#define MFMA_BF16(a, b, c) __builtin_amdgcn_mfma_f32_16x16x32_bf16((a), (b), (c), 0, 0, 0)

#if defined(__has_builtin)
# if __has_builtin(__builtin_amdgcn_exp2f)
#  define EXP2(x) __builtin_amdgcn_exp2f(x)
# else
#  define EXP2(x) exp2f(x)
# endif
#else
# define EXP2(x) exp2f(x)
#endif

#define K_E 0.18033688f      // 0.125 * log2(e)
#define K_EINV 5.5451774f    // 1 / K_E

__device__ __forceinline__ int swz128(int row, int colByte) {
    return row * 128 + (colByte ^ ((row & 7) << 4));
}
__device__ __forceinline__ int swz512(int row, int colByte) {
    return row * 512 + (colByte ^ ((row & 15) << 4));
}

// LDS union offsets for K_A
#define OW_W   0
#define OW_WR  32768
#define OW_WD  40960
#define OT_C   0
#define OT_R   16384
#define OT_D   20480
#define O_S1   49152
#define O_B1   49408
#define O_RED  49664
#define SMEMA  51712

// ---------------------------------------------------------------------------
// K_A: self-staged weights -> conv+BN+ReLU -> proj -> fragment-order stores.
// prF/pdF: f(i,c) = (i>>4)*1024 + (c>>3)*128 + (i&15)*8 + (c&7)   (per batch)
// ---------------------------------------------------------------------------
__global__ __launch_bounds__(512, 2) void k_front(
    const float* __restrict__ rgb, const float* __restrict__ dep,
    const float* __restrict__ conv_w,
    const float* __restrict__ bn1_g, const float* __restrict__ bn1_b,
    const float* __restrict__ bn1_m, const float* __restrict__ bn1_v,
    const float* __restrict__ rgb_w, const float* __restrict__ dep_w,
    bf16* __restrict__ prF, bf16* __restrict__ pdF,
    float* __restrict__ rgbdPart, int* __restrict__ counter)
{
    const int bid = blockIdx.x;
    const int xcd = bid & 7;
    const int b    = xcd >> 1;
    const int tile = ((bid >> 3) << 1) | (xcd & 1);
    const int p0   = tile * 32;
    const int tid = threadIdx.x;
    const int w   = tid >> 6;
    const int lane = tid & 63;
    const int l15 = lane & 15;
    const int lg  = lane >> 4;
    const int ot4 = w & 3;
    const int ot  = ot4 * 16;
    const int ph  = w >> 2;

    if (bid == 0 && tid == 0) *counter = 0;

    __shared__ __align__(16) unsigned char smem[SMEMA];
    float* s1 = (float*)(smem + O_S1);
    float* b1 = (float*)(smem + O_B1);
    float* red = (float*)(smem + O_RED);

    // ---- phase W: stage all weights coalesced -> swizzled LDS bf16 ----
    {
        unsigned char* ldsW  = smem + OW_W;
        unsigned char* ldsWR = smem + OW_WR;
        unsigned char* ldsWD = smem + OW_WD;
        #pragma unroll
        for (int q = 0; q < 8; ++q) {
            const int idx = (q * 512 + tid) * 4;
            float4v v = *(const float4v*)(conv_w + idx);
            const int o = idx >> 8, c = idx & 255;
            bf16x4 h;
            #pragma unroll
            for (int j = 0; j < 4; ++j) h[j] = (bf16)v[j];
            *(bf16x4*)(ldsW + swz512(o, c * 2)) = h;
        }
        #pragma unroll
        for (int q = 0; q < 2; ++q) {
            const int idx = (q * 512 + tid) * 4;
            const int o = idx >> 6, c = idx & 63;
            float4v v = *(const float4v*)(rgb_w + idx);
            bf16x4 h;
            #pragma unroll
            for (int j = 0; j < 4; ++j) h[j] = (bf16)v[j];
            *(bf16x4*)(ldsWR + swz128(o, c * 2)) = h;
            v = *(const float4v*)(dep_w + idx);
            #pragma unroll
            for (int j = 0; j < 4; ++j) h[j] = (bf16)v[j];
            *(bf16x4*)(ldsWD + swz128(o, c * 2)) = h;
        }
        if (tid < 64) {
            float sc = bn1_g[tid] * rsqrtf(bn1_v[tid] + 1e-5f);
            s1[tid] = sc;
            b1[tid] = bn1_b[tid] - bn1_m[tid] * sc;
        }
    }
    __syncthreads();

    // ---- fragments -> registers ----
    bf16x8 aW[8], aR[2], aD[2];
    {
        const unsigned char* ldsW  = smem + OW_W;
        const unsigned char* ldsWR = smem + OW_WR;
        const unsigned char* ldsWD = smem + OW_WD;
        const int row = ot + l15;
        #pragma unroll
        for (int kk = 0; kk < 8; ++kk)
            aW[kk] = *(const bf16x8*)(ldsW + swz512(row, (kk * 32 + lg * 8) * 2));
        #pragma unroll
        for (int kk = 0; kk < 2; ++kk) {
            aR[kk] = *(const bf16x8*)(ldsWR + swz128(row, (kk * 32 + lg * 8) * 2));
            aD[kk] = *(const bf16x8*)(ldsWD + swz128(row, (kk * 32 + lg * 8) * 2));
        }
    }
    __syncthreads();

    // ---- phase T: stage dep/rgb tiles coalesced ----
    unsigned char* ldsC = smem + OT_C;
    unsigned char* ldsR = smem + OT_R;
    unsigned char* ldsD = smem + OT_D;
    const float* depb = dep + (size_t)b * 256 * 4096;
    const float* rgbb = rgb + (size_t)b * 64 * 4096;
    {
        const int c0 = tid >> 3, seg = tid & 7;
        #pragma unroll
        for (int r = 0; r < 4; ++r) {
            const int c = r * 64 + c0;
            float4v v = *(const float4v*)(depb + (size_t)c * 4096 + p0 + seg * 4);
            #pragma unroll
            for (int k = 0; k < 4; ++k)
                *(bf16*)(ldsC + swz512(seg * 4 + k, c * 2)) = (bf16)v[k];
        }
        float4v v = *(const float4v*)(rgbb + (size_t)c0 * 4096 + p0 + seg * 4);
        #pragma unroll
        for (int k = 0; k < 4; ++k)
            *(bf16*)(ldsR + swz128(seg * 4 + k, c0 * 2)) = (bf16)v[k];
    }
    __syncthreads();

    // ---- conv MFMA K=256 ----
    const int prow = ph * 16 + l15;
    f32x4 acc = {0.f, 0.f, 0.f, 0.f};
    #pragma unroll
    for (int kk = 0; kk < 8; ++kk) {
        bf16x8 bF = *(const bf16x8*)(ldsC + swz512(prow, (kk * 32 + lg * 8) * 2));
        acc = MFMA_BF16(aW[kk], bF, acc);
    }
    {
        const int o0 = ot + lg * 4;
        bf16x4 v4;
        #pragma unroll
        for (int r = 0; r < 4; ++r) {
            float x = acc[r] * s1[o0 + r] + b1[o0 + r];
            v4[r] = (bf16)(x > 0.f ? x : 0.f);
        }
        *(bf16x4*)(ldsD + swz128(prow, o0 * 2)) = v4;
    }
    __syncthreads();

    // ---- proj GEMMs (K=64) + fragment-order stores ----
    f32x4 accR = {0.f, 0.f, 0.f, 0.f}, accD = {0.f, 0.f, 0.f, 0.f};
    #pragma unroll
    for (int kk = 0; kk < 2; ++kk) {
        const int cb = (kk * 32 + lg * 8) * 2;
        bf16x8 bR = *(const bf16x8*)(ldsR + swz128(prow, cb));
        bf16x8 bD = *(const bf16x8*)(ldsD + swz128(prow, cb));
        accR = MFMA_BF16(aR[kk], bR, accR);
        accD = MFMA_BF16(aD[kk], bD, accD);
    }
    {
        const int o0 = ot + lg * 4;
        const size_t itile = (size_t)tile * 2 + ph;
        const size_t fbase = (size_t)b * 262144 + itile * 1024;
        const size_t prOff = fbase + (size_t)(o0 >> 3) * 128 + l15 * 8 + (o0 & 7);
        bf16x4 vR, vD;
        #pragma unroll
        for (int r = 0; r < 4; ++r) {
            vR[r] = (bf16)(accR[r] * K_E);
            vD[r] = (bf16)accD[r];
        }
        *(bf16x4*)(prF + prOff) = vR;
        *(bf16x4*)(pdF + prOff) = vD;
    }

    // ---- rgbd per-tile sums ----
    {
        const int c = tid & 63, g8 = tid >> 6;
        float sum = 0.f;
        #pragma unroll
        for (int q = 0; q < 4; ++q) {
            const int pp = g8 * 4 + q;
            sum += (float)*(const bf16*)(ldsR + swz128(pp, c * 2))
                 + (float)*(const bf16*)(ldsD + swz128(pp, c * 2));
        }
        red[g8 * 64 + c] = sum;
    }
    __syncthreads();
    if (tid < 64) {
        float s = 0.f;
        #pragma unroll
        for (int g = 0; g < 8; ++g) s += red[g * 64 + tid];
        rgbdPart[((size_t)b * 128 + tile) * 64 + tid] = s;
    }
}

// ---------------------------------------------------------------------------
// K_Z: Z partials over 512x512 tiles. Grid 256 = b(4) x jc(8) x ic(8),
// 512 thr, lb(512,2) (128-reg cap; LDS 64KB -> 2 blk/CU anyway).
// ---------------------------------------------------------------------------
__global__ __launch_bounds__(512, 2) void k_z(
    const bf16* __restrict__ prF, const bf16* __restrict__ pdF,
    float* __restrict__ Zpart)
{
    const int bid = blockIdx.x;
    const int b = bid >> 6, rest = bid & 63;
    const int jc = rest >> 3, ic = rest & 7;
    const int tid = threadIdx.x, w = tid >> 6, lane = tid & 63;

    __shared__ __align__(16) bf16 pdL[32768];   // 64KB j-chunk

    const bf16* prb = prF + (size_t)b * 262144;
    const bf16* pdb = pdF + (size_t)b * 262144;

    // stage pd j-chunk (fragment order is contiguous per chunk)
    {
        const i32x4* src = (const i32x4*)(pdb + (size_t)jc * 32768);
        i32x4* dst = (i32x4*)pdL;
        #pragma unroll
        for (int q = 0; q < 8; ++q)
            dst[q * 512 + tid] = src[q * 512 + tid];
    }
    // resident A-frags: 4 i-tiles per wave
    bf16x8 A0[4], A1[4];
    #pragma unroll
    for (int it = 0; it < 4; ++it) {
        const bf16* p = prb + (size_t)(ic * 32 + w * 4 + it) * 1024 + lane * 8;
        A0[it] = *(const bf16x8*)p;
        A1[it] = *(const bf16x8*)(p + 512);
    }
    __syncthreads();

    float zacc[32];
    #pragma unroll
    for (int jt = 0; jt < 32; ++jt) zacc[jt] = 0.f;

    #pragma unroll
    for (int jt = 0; jt < 32; ++jt) {
        bf16x8 B0 = *(const bf16x8*)(pdL + jt * 1024 + lane * 8);
        bf16x8 B1 = *(const bf16x8*)(pdL + jt * 1024 + 512 + lane * 8);
        #pragma unroll
        for (int it = 0; it < 4; ++it) {
            f32x4 e = {0.f, 0.f, 0.f, 0.f};
            e = MFMA_BF16(A0[it], B0, e);
            e = MFMA_BF16(A1[it], B1, e);
            zacc[jt] += (EXP2(e[0]) + EXP2(e[1])) + (EXP2(e[2]) + EXP2(e[3]));
        }
    }
    __syncthreads();            // pdL fully consumed; reuse as zred
    float* zred = (float*)pdL;  // [8][512]
    #pragma unroll
    for (int jt = 0; jt < 32; ++jt) {
        float v = zacc[jt];
        v += __shfl_xor(v, 16);
        v += __shfl_xor(v, 32);
        if (lane < 16) zred[w * 512 + jt * 16 + lane] = v;
    }
    __syncthreads();
    {
        float s = 0.f;
        #pragma unroll
        for (int k = 0; k < 8; ++k) s += zred[k * 512 + tid];
        Zpart[((size_t)ic * 4 + b) * 4096 + jc * 512 + tid] = s;
    }
}

// ---------------------------------------------------------------------------
// K_S: s partials over 512x512 tiles + fused gap contribution + gate.
// Grid 256 = b(4) x jc(8) x ic(8), 512 thr, lb(512,2).
// ---------------------------------------------------------------------------
__global__ __launch_bounds__(512, 2) void k_s(
    const bf16* __restrict__ prF, const bf16* __restrict__ pdF,
    const float* __restrict__ Zpart,
    float* __restrict__ gapPart, const float* __restrict__ rgbdPart,
    int* __restrict__ counter,
    const float* __restrict__ mlp1_w,
    const float* __restrict__ bn2_g, const float* __restrict__ bn2_b,
    const float* __restrict__ bn2_m, const float* __restrict__ bn2_v,
    const float* __restrict__ mlp2_w,
    const float* __restrict__ bn3_g, const float* __restrict__ bn3_b,
    const float* __restrict__ bn3_m, const float* __restrict__ bn3_v,
    float* __restrict__ out)
{
    const int bid = blockIdx.x;
    const int b = bid >> 6, rest = bid & 63;
    const int jc = rest >> 3, ic = rest & 7;
    const int tid = threadIdx.x, w = tid >> 6, lane = tid & 63;
    const int l15 = lane & 15, lg = lane >> 4;

    __shared__ __align__(16) bf16 pdL[32768];   // 64KB
    __shared__ float zinv_lds[512];
    __shared__ float s_lds[512];
    __shared__ float gred[8][64];
    __shared__ float gv4[4][64];
    __shared__ float h4[4][24];
    __shared__ int winflag;
    if (tid == 0) winflag = 0;

    const bf16* prb = prF + (size_t)b * 262144;
    const bf16* pdb = pdF + (size_t)b * 262144;

    // stage pd j-chunk
    {
        const i32x4* src = (const i32x4*)(pdb + (size_t)jc * 32768);
        i32x4* dst = (i32x4*)pdL;
        #pragma unroll
        for (int q = 0; q < 8; ++q)
            dst[q * 512 + tid] = src[q * 512 + tid];
    }
    // zinv prologue: thread t -> j = jc*512 + t
    {
        const float* zp = Zpart + (size_t)b * 4096 + jc * 512 + tid;
        float s = 0.f;
        #pragma unroll
        for (int k = 0; k < 8; ++k) s += zp[(size_t)k * 16384];
        float zi = __builtin_amdgcn_rcpf(s);
        zinv_lds[tid] = zi * (2.0f - s * zi);
    }
    // resident A-frags
    bf16x8 A0[4], A1[4];
    #pragma unroll
    for (int it = 0; it < 4; ++it) {
        const bf16* p = prb + (size_t)(ic * 32 + w * 4 + it) * 1024 + lane * 8;
        A0[it] = *(const bf16x8*)p;
        A1[it] = *(const bf16x8*)(p + 512);
    }
    __syncthreads();

    float sacc[4][4] = {};
    #pragma unroll
    for (int jt = 0; jt < 32; ++jt) {
        bf16x8 B0 = *(const bf16x8*)(pdL + jt * 1024 + lane * 8);
        bf16x8 B1 = *(const bf16x8*)(pdL + jt * 1024 + 512 + lane * 8);
        const float zv = zinv_lds[jt * 16 + l15];
        #pragma unroll
        for (int it = 0; it < 4; ++it) {
            f32x4 e = {0.f, 0.f, 0.f, 0.f};
            e = MFMA_BF16(A0[it], B0, e);
            e = MFMA_BF16(A1[it], B1, e);
            sacc[it][0] += EXP2(e[0]) * zv;
            sacc[it][1] += EXP2(e[1]) * zv;
            sacc[it][2] += EXP2(e[2]) * zv;
            sacc[it][3] += EXP2(e[3]) * zv;
        }
    }
    // phase-1 epilogue: s per row -> s_lds
    #pragma unroll
    for (int it = 0; it < 4; ++it) {
        #pragma unroll
        for (int r = 0; r < 4; ++r) {
            float v = sacc[it][r];
            v += __shfl_xor(v, 1);
            v += __shfl_xor(v, 2);
            v += __shfl_xor(v, 4);
            v += __shfl_xor(v, 8);
            if (l15 == 0) s_lds[w * 64 + it * 16 + lg * 4 + r] = v;
        }
    }
    __syncthreads();

    // phase 2: gap partial = sum_i s_i * (K_EINV*pr_e[i,c] + pd[i,c])
    float g0[8] = {}, g1[8] = {};
    #pragma unroll
    for (int it = 0; it < 4; ++it) {
        const bf16* p = pdb + (size_t)(ic * 32 + w * 4 + it) * 1024 + lane * 8;
        bf16x8 PD0 = *(const bf16x8*)p;
        bf16x8 PD1 = *(const bf16x8*)(p + 512);
        const float sv = s_lds[w * 64 + it * 16 + l15];
        #pragma unroll
        for (int k = 0; k < 8; ++k) {
            g0[k] += sv * (K_EINV * (float)A0[it][k] + (float)PD0[k]);
            g1[k] += sv * (K_EINV * (float)A1[it][k] + (float)PD1[k]);
        }
    }
    #pragma unroll
    for (int k = 0; k < 8; ++k) {
        float v0 = g0[k], v1 = g1[k];
        v0 += __shfl_xor(v0, 1);
        v0 += __shfl_xor(v0, 2);
        v0 += __shfl_xor(v0, 4);
        v0 += __shfl_xor(v0, 8);
        v1 += __shfl_xor(v1, 1);
        v1 += __shfl_xor(v1, 2);
        v1 += __shfl_xor(v1, 4);
        v1 += __shfl_xor(v1, 8);
        if (l15 == 0) {
            gred[w][lg * 8 + k] = v0;
            gred[w][32 + lg * 8 + k] = v1;
        }
    }
    __syncthreads();
    if (tid < 64) {
        float s = 0.f;
        #pragma unroll
        for (int k = 0; k < 8; ++k) s += gred[k][tid];
        gapPart[((size_t)b * 64 + jc * 8 + ic) * 64 + tid] = s;
        __threadfence();
        int old = atomicAdd(counter, 1);
        if (old == 256 * 64 - 1) winflag = 1;
    }
    __syncthreads();

    // ================= last block: MLP gate ==================
    if (winflag) {
        __threadfence();
        const int wb = w >> 1, half = w & 1;
        float acc2 = 0.f;
        const float* gp = gapPart + ((size_t)wb * 64 + half * 32) * 64 + lane;
        #pragma unroll 4
        for (int r = 0; r < 32; ++r) acc2 += gp[r * 64];
        const float* rp = rgbdPart + ((size_t)wb * 128 + half * 64) * 64 + lane;
        #pragma unroll 4
        for (int r = 0; r < 64; ++r) acc2 += rp[r * 64];
        gred[w][lane] = acc2;
        __syncthreads();
        if (tid < 256) {
            const int b4 = tid >> 6, c = tid & 63;
            gv4[b4][c] = (gred[2 * b4][c] + gred[2 * b4 + 1][c]) * (1.f / 4096.f);
        }
        __syncthreads();
        if (tid < 96) {
            const int b4 = tid / 24, o = tid % 24;
            float a = 0.f;
            #pragma unroll
            for (int cc = 0; cc < 64; ++cc) a += mlp1_w[o * 64 + cc] * gv4[b4][cc];
            float sc = bn2_g[o] * rsqrtf(bn2_v[o] + 1e-5f);
            a = a * sc + bn2_b[o] - bn2_m[o] * sc;
            h4[b4][o] = a > 0.f ? a : 0.f;
        }
        __syncthreads();
        if (tid < 256) {
            const int b4 = tid >> 6, c = tid & 63;
            float u = 0.f;
            #pragma unroll
            for (int o = 0; o < 24; ++o) u += mlp2_w[c * 24 + o] * h4[b4][o];
            float sc = bn3_g[c] * rsqrtf(bn3_v[c] + 1e-5f);
            u = u * sc + bn3_b[c] - bn3_m[c] * sc;
            out[b4 * 64 + c] = 1.f / (1.f + __expf(-u));
        }
    }
}

// ---------------------------------------------------------------------------
extern "C" void kernel_launch(void* const* d_in, const int* in_sizes, int n_in,
                              void* d_out, int out_size, void* d_ws, size_t ws_size,
                              hipStream_t stream)
{
    const float* rgb    = (const float*)d_in[0];
    const float* dep    = (const float*)d_in[1];
    const float* conv_w = (const float*)d_in[2];
    const float* bn1_g  = (const float*)d_in[3];
    const float* bn1_b  = (const float*)d_in[4];
    const float* bn1_m  = (const float*)d_in[5];
    const float* bn1_v  = (const float*)d_in[6];
    const float* rgb_w  = (const float*)d_in[7];
    const float* dep_w  = (const float*)d_in[8];
    const float* mlp1_w = (const float*)d_in[9];
    const float* bn2_g  = (const float*)d_in[10];
    const float* bn2_b  = (const float*)d_in[11];
    const float* bn2_m  = (const float*)d_in[12];
    const float* bn2_v  = (const float*)d_in[13];
    const float* mlp2_w = (const float*)d_in[14];
    const float* bn3_g  = (const float*)d_in[15];
    const float* bn3_b  = (const float*)d_in[16];
    const float* bn3_m  = (const float*)d_in[17];
    const float* bn3_v  = (const float*)d_in[18];

    char* ws = (char*)d_ws;
    bf16*  prF      = (bf16*)(ws);                                  // 2 MB
    bf16*  pdF      = (bf16*)(ws + (2u << 20));                     // 2 MB
    float* Zpart    = (float*)(ws + (4u << 20));                    // 512 KB
    float* rgbdPart = (float*)(ws + (4u << 20) + (512u << 10));     // 128 KB
    float* gapPart  = (float*)(ws + (4u << 20) + (640u << 10));     // 64 KB
    int*   counter  = (int*)  (ws + (4u << 20) + (704u << 10));     // 4 B

    k_front<<<512, 512, 0, stream>>>(rgb, dep, conv_w,
                                     bn1_g, bn1_b, bn1_m, bn1_v,
                                     rgb_w, dep_w,
                                     prF, pdF, rgbdPart, counter);
    k_z<<<256, 512, 0, stream>>>(prF, pdF, Zpart);
    k_s<<<256, 512, 0, stream>>>(prF, pdF, Zpart, gapPart, rgbdPart, counter,
                                 mlp1_w, bn2_g, bn2_b, bn2_m, bn2_v,
                                 mlp2_w, bn3_g, bn3_b, bn3_m, bn3_v,
                                 (float*)d_out);
}

// Round 19
// 69.431 us; speedup vs baseline: 4.7266x; 3.0324x over previous
//
#include <hip/hip_runtime.h>
#include <hip/hip_bf16.h>

// ---------------------------------------------------------------------------
// R19: R18 with UNROLL DISCIPLINE (spill root cause found).
// R18 evidence: k_s VGPR pinned at the 128 cap + 287MB FETCH / 160MB WRITE
// scratch => true register demand >128. Cause: full `#pragma unroll` on the
// 32-iter jt loop let the scheduler hoist dozens of 8-VGPR B-frag LDS loads
// into overlapping live ranges. Fix: `#pragma unroll 2` on jt loops in
// k_z/k_s (live transients ~2x8 regs; static state ~80 regs; total ~110).
// Algorithm unchanged (two-pass, 512x512 tiles, 33MB/pass — first clean run).
//   k_front: conv+proj -> fragment-order prF/pdF + rgbd partials + ctr=0
//   k_z:     grid 256 = 4b x 8jc x 8ic; Z partials
//   k_s:     same grid; s partials; phase-2 folds gap; last-block MLP gate.
// Math validated R3-R7 (two-pass) + R11 (fragment layouts): absmax 0.0039.
// ---------------------------------------------------------------------------

typedef __bf16 bf16;
typedef __bf16 bf16x4 __attribute__((ext_vector_type(4)));
typedef __bf16 bf16x8 __attribute__((ext_vector_type(8)));
typedef float  f32x4  __attribute__((ext_vector_type(4)));
typedef float  float4v __attribute__((ext_vector_type(4)));
typedef int    i32x4  __attribute__((ext_vector_type(4)));

#define MFMA_BF16(a, b, c) __builtin_amdgcn_mfma_f32_16x16x32_bf16((a), (b), (c), 0, 0, 0)

#if defined(__has_builtin)
# if __has_builtin(__builtin_amdgcn_exp2f)
#  define EXP2(x) __builtin_amdgcn_exp2f(x)
# else
#  define EXP2(x) exp2f(x)
# endif
#else
# define EXP2(x) exp2f(x)
#endif

#define K_E 0.18033688f      // 0.125 * log2(e)
#define K_EINV 5.5451774f    // 1 / K_E

__device__ __forceinline__ int swz128(int row, int colByte) {
    return row * 128 + (colByte ^ ((row & 7) << 4));
}
__device__ __forceinline__ int swz512(int row, int colByte) {
    return row * 512 + (colByte ^ ((row & 15) << 4));
}

// LDS union offsets for K_A
#define OW_W   0
#define OW_WR  32768
#define OW_WD  40960
#define OT_C   0
#define OT_R   16384
#define OT_D   20480
#define O_S1   49152
#define O_B1   49408
#define O_RED  49664
#define SMEMA  51712

// ---------------------------------------------------------------------------
// K_A: self-staged weights -> conv+BN+ReLU -> proj -> fragment-order stores.
// prF/pdF: f(i,c) = (i>>4)*1024 + (c>>3)*128 + (i&15)*8 + (c&7)   (per batch)
// ---------------------------------------------------------------------------
__global__ __launch_bounds__(512, 2) void k_front(
    const float* __restrict__ rgb, const float* __restrict__ dep,
    const float* __restrict__ conv_w,
    const float* __restrict__ bn1_g, const float* __restrict__ bn1_b,
    const float* __restrict__ bn1_m, const float* __restrict__ bn1_v,
    const float* __restrict__ rgb_w, const float* __restrict__ dep_w,
    bf16* __restrict__ prF, bf16* __restrict__ pdF,
    float* __restrict__ rgbdPart, int* __restrict__ counter)
{
    const int bid = blockIdx.x;
    const int xcd = bid & 7;
    const int b    = xcd >> 1;
    const int tile = ((bid >> 3) << 1) | (xcd & 1);
    const int p0   = tile * 32;
    const int tid = threadIdx.x;
    const int w   = tid >> 6;
    const int lane = tid & 63;
    const int l15 = lane & 15;
    const int lg  = lane >> 4;
    const int ot4 = w & 3;
    const int ot  = ot4 * 16;
    const int ph  = w >> 2;

    if (bid == 0 && tid == 0) *counter = 0;

    __shared__ __align__(16) unsigned char smem[SMEMA];
    float* s1 = (float*)(smem + O_S1);
    float* b1 = (float*)(smem + O_B1);
    float* red = (float*)(smem + O_RED);

    // ---- phase W: stage all weights coalesced -> swizzled LDS bf16 ----
    {
        unsigned char* ldsW  = smem + OW_W;
        unsigned char* ldsWR = smem + OW_WR;
        unsigned char* ldsWD = smem + OW_WD;
        #pragma unroll
        for (int q = 0; q < 8; ++q) {
            const int idx = (q * 512 + tid) * 4;
            float4v v = *(const float4v*)(conv_w + idx);
            const int o = idx >> 8, c = idx & 255;
            bf16x4 h;
            #pragma unroll
            for (int j = 0; j < 4; ++j) h[j] = (bf16)v[j];
            *(bf16x4*)(ldsW + swz512(o, c * 2)) = h;
        }
        #pragma unroll
        for (int q = 0; q < 2; ++q) {
            const int idx = (q * 512 + tid) * 4;
            const int o = idx >> 6, c = idx & 63;
            float4v v = *(const float4v*)(rgb_w + idx);
            bf16x4 h;
            #pragma unroll
            for (int j = 0; j < 4; ++j) h[j] = (bf16)v[j];
            *(bf16x4*)(ldsWR + swz128(o, c * 2)) = h;
            v = *(const float4v*)(dep_w + idx);
            #pragma unroll
            for (int j = 0; j < 4; ++j) h[j] = (bf16)v[j];
            *(bf16x4*)(ldsWD + swz128(o, c * 2)) = h;
        }
        if (tid < 64) {
            float sc = bn1_g[tid] * rsqrtf(bn1_v[tid] + 1e-5f);
            s1[tid] = sc;
            b1[tid] = bn1_b[tid] - bn1_m[tid] * sc;
        }
    }
    __syncthreads();

    // ---- fragments -> registers ----
    bf16x8 aW[8], aR[2], aD[2];
    {
        const unsigned char* ldsW  = smem + OW_W;
        const unsigned char* ldsWR = smem + OW_WR;
        const unsigned char* ldsWD = smem + OW_WD;
        const int row = ot + l15;
        #pragma unroll
        for (int kk = 0; kk < 8; ++kk)
            aW[kk] = *(const bf16x8*)(ldsW + swz512(row, (kk * 32 + lg * 8) * 2));
        #pragma unroll
        for (int kk = 0; kk < 2; ++kk) {
            aR[kk] = *(const bf16x8*)(ldsWR + swz128(row, (kk * 32 + lg * 8) * 2));
            aD[kk] = *(const bf16x8*)(ldsWD + swz128(row, (kk * 32 + lg * 8) * 2));
        }
    }
    __syncthreads();

    // ---- phase T: stage dep/rgb tiles coalesced ----
    unsigned char* ldsC = smem + OT_C;
    unsigned char* ldsR = smem + OT_R;
    unsigned char* ldsD = smem + OT_D;
    const float* depb = dep + (size_t)b * 256 * 4096;
    const float* rgbb = rgb + (size_t)b * 64 * 4096;
    {
        const int c0 = tid >> 3, seg = tid & 7;
        #pragma unroll
        for (int r = 0; r < 4; ++r) {
            const int c = r * 64 + c0;
            float4v v = *(const float4v*)(depb + (size_t)c * 4096 + p0 + seg * 4);
            #pragma unroll
            for (int k = 0; k < 4; ++k)
                *(bf16*)(ldsC + swz512(seg * 4 + k, c * 2)) = (bf16)v[k];
        }
        float4v v = *(const float4v*)(rgbb + (size_t)c0 * 4096 + p0 + seg * 4);
        #pragma unroll
        for (int k = 0; k < 4; ++k)
            *(bf16*)(ldsR + swz128(seg * 4 + k, c0 * 2)) = (bf16)v[k];
    }
    __syncthreads();

    // ---- conv MFMA K=256 ----
    const int prow = ph * 16 + l15;
    f32x4 acc = {0.f, 0.f, 0.f, 0.f};
    #pragma unroll
    for (int kk = 0; kk < 8; ++kk) {
        bf16x8 bF = *(const bf16x8*)(ldsC + swz512(prow, (kk * 32 + lg * 8) * 2));
        acc = MFMA_BF16(aW[kk], bF, acc);
    }
    {
        const int o0 = ot + lg * 4;
        bf16x4 v4;
        #pragma unroll
        for (int r = 0; r < 4; ++r) {
            float x = acc[r] * s1[o0 + r] + b1[o0 + r];
            v4[r] = (bf16)(x > 0.f ? x : 0.f);
        }
        *(bf16x4*)(ldsD + swz128(prow, o0 * 2)) = v4;
    }
    __syncthreads();

    // ---- proj GEMMs (K=64) + fragment-order stores ----
    f32x4 accR = {0.f, 0.f, 0.f, 0.f}, accD = {0.f, 0.f, 0.f, 0.f};
    #pragma unroll
    for (int kk = 0; kk < 2; ++kk) {
        const int cb = (kk * 32 + lg * 8) * 2;
        bf16x8 bR = *(const bf16x8*)(ldsR + swz128(prow, cb));
        bf16x8 bD = *(const bf16x8*)(ldsD + swz128(prow, cb));
        accR = MFMA_BF16(aR[kk], bR, accR);
        accD = MFMA_BF16(aD[kk], bD, accD);
    }
    {
        const int o0 = ot + lg * 4;
        const size_t itile = (size_t)tile * 2 + ph;
        const size_t fbase = (size_t)b * 262144 + itile * 1024;
        const size_t prOff = fbase + (size_t)(o0 >> 3) * 128 + l15 * 8 + (o0 & 7);
        bf16x4 vR, vD;
        #pragma unroll
        for (int r = 0; r < 4; ++r) {
            vR[r] = (bf16)(accR[r] * K_E);
            vD[r] = (bf16)accD[r];
        }
        *(bf16x4*)(prF + prOff) = vR;
        *(bf16x4*)(pdF + prOff) = vD;
    }

    // ---- rgbd per-tile sums ----
    {
        const int c = tid & 63, g8 = tid >> 6;
        float sum = 0.f;
        #pragma unroll
        for (int q = 0; q < 4; ++q) {
            const int pp = g8 * 4 + q;
            sum += (float)*(const bf16*)(ldsR + swz128(pp, c * 2))
                 + (float)*(const bf16*)(ldsD + swz128(pp, c * 2));
        }
        red[g8 * 64 + c] = sum;
    }
    __syncthreads();
    if (tid < 64) {
        float s = 0.f;
        #pragma unroll
        for (int g = 0; g < 8; ++g) s += red[g * 64 + tid];
        rgbdPart[((size_t)b * 128 + tile) * 64 + tid] = s;
    }
}

// ---------------------------------------------------------------------------
// K_Z: Z partials over 512x512 tiles. Grid 256 = b(4) x jc(8) x ic(8),
// 512 thr, lb(512,2). jt loop unroll-capped at 2 (spill discipline).
// ---------------------------------------------------------------------------
__global__ __launch_bounds__(512, 2) void k_z(
    const bf16* __restrict__ prF, const bf16* __restrict__ pdF,
    float* __restrict__ Zpart)
{
    const int bid = blockIdx.x;
    const int b = bid >> 6, rest = bid & 63;
    const int jc = rest >> 3, ic = rest & 7;
    const int tid = threadIdx.x, w = tid >> 6, lane = tid & 63;

    __shared__ __align__(16) bf16 pdL[32768];   // 64KB j-chunk

    const bf16* prb = prF + (size_t)b * 262144;
    const bf16* pdb = pdF + (size_t)b * 262144;

    // stage pd j-chunk (fragment order is contiguous per chunk)
    {
        const i32x4* src = (const i32x4*)(pdb + (size_t)jc * 32768);
        i32x4* dst = (i32x4*)pdL;
        #pragma unroll
        for (int q = 0; q < 8; ++q)
            dst[q * 512 + tid] = src[q * 512 + tid];
    }
    // resident A-frags: 4 i-tiles per wave
    bf16x8 A0[4], A1[4];
    #pragma unroll
    for (int it = 0; it < 4; ++it) {
        const bf16* p = prb + (size_t)(ic * 32 + w * 4 + it) * 1024 + lane * 8;
        A0[it] = *(const bf16x8*)p;
        A1[it] = *(const bf16x8*)(p + 512);
    }
    __syncthreads();

    float zacc[32];
    #pragma unroll
    for (int jt = 0; jt < 32; ++jt) zacc[jt] = 0.f;

    #pragma unroll 2
    for (int jt = 0; jt < 32; ++jt) {
        bf16x8 B0 = *(const bf16x8*)(pdL + jt * 1024 + lane * 8);
        bf16x8 B1 = *(const bf16x8*)(pdL + jt * 1024 + 512 + lane * 8);
        #pragma unroll
        for (int it = 0; it < 4; ++it) {
            f32x4 e = {0.f, 0.f, 0.f, 0.f};
            e = MFMA_BF16(A0[it], B0, e);
            e = MFMA_BF16(A1[it], B1, e);
            zacc[jt] += (EXP2(e[0]) + EXP2(e[1])) + (EXP2(e[2]) + EXP2(e[3]));
        }
    }
    __syncthreads();            // pdL fully consumed; reuse as zred
    float* zred = (float*)pdL;  // [8][512]
    #pragma unroll 4
    for (int jt = 0; jt < 32; ++jt) {
        float v = zacc[jt];
        v += __shfl_xor(v, 16);
        v += __shfl_xor(v, 32);
        if (lane < 16) zred[w * 512 + jt * 16 + lane] = v;
    }
    __syncthreads();
    {
        float s = 0.f;
        #pragma unroll
        for (int k = 0; k < 8; ++k) s += zred[k * 512 + tid];
        Zpart[((size_t)ic * 4 + b) * 4096 + jc * 512 + tid] = s;
    }
}

// ---------------------------------------------------------------------------
// K_S: s partials over 512x512 tiles + fused gap contribution + gate.
// Grid 256 = b(4) x jc(8) x ic(8), 512 thr, lb(512,2), jt unroll 2.
// ---------------------------------------------------------------------------
__global__ __launch_bounds__(512, 2) void k_s(
    const bf16* __restrict__ prF, const bf16* __restrict__ pdF,
    const float* __restrict__ Zpart,
    float* __restrict__ gapPart, const float* __restrict__ rgbdPart,
    int* __restrict__ counter,
    const float* __restrict__ mlp1_w,
    const float* __restrict__ bn2_g, const float* __restrict__ bn2_b,
    const float* __restrict__ bn2_m, const float* __restrict__ bn2_v,
    const float* __restrict__ mlp2_w,
    const float* __restrict__ bn3_g, const float* __restrict__ bn3_b,
    const float* __restrict__ bn3_m, const float* __restrict__ bn3_v,
    float* __restrict__ out)
{
    const int bid = blockIdx.x;
    const int b = bid >> 6, rest = bid & 63;
    const int jc = rest >> 3, ic = rest & 7;
    const int tid = threadIdx.x, w = tid >> 6, lane = tid & 63;
    const int l15 = lane & 15, lg = lane >> 4;

    __shared__ __align__(16) bf16 pdL[32768];   // 64KB
    __shared__ float zinv_lds[512];
    __shared__ float s_lds[512];
    __shared__ float gred[8][64];
    __shared__ float gv4[4][64];
    __shared__ float h4[4][24];
    __shared__ int winflag;
    if (tid == 0) winflag = 0;

    const bf16* prb = prF + (size_t)b * 262144;
    const bf16* pdb = pdF + (size_t)b * 262144;

    // stage pd j-chunk
    {
        const i32x4* src = (const i32x4*)(pdb + (size_t)jc * 32768);
        i32x4* dst = (i32x4*)pdL;
        #pragma unroll
        for (int q = 0; q < 8; ++q)
            dst[q * 512 + tid] = src[q * 512 + tid];
    }
    // zinv prologue: thread t -> j = jc*512 + t
    {
        const float* zp = Zpart + (size_t)b * 4096 + jc * 512 + tid;
        float s = 0.f;
        #pragma unroll
        for (int k = 0; k < 8; ++k) s += zp[(size_t)k * 16384];
        float zi = __builtin_amdgcn_rcpf(s);
        zinv_lds[tid] = zi * (2.0f - s * zi);
    }
    // resident A-frags
    bf16x8 A0[4], A1[4];
    #pragma unroll
    for (int it = 0; it < 4; ++it) {
        const bf16* p = prb + (size_t)(ic * 32 + w * 4 + it) * 1024 + lane * 8;
        A0[it] = *(const bf16x8*)p;
        A1[it] = *(const bf16x8*)(p + 512);
    }
    __syncthreads();

    float sacc[4][4] = {};
    #pragma unroll 2
    for (int jt = 0; jt < 32; ++jt) {
        bf16x8 B0 = *(const bf16x8*)(pdL + jt * 1024 + lane * 8);
        bf16x8 B1 = *(const bf16x8*)(pdL + jt * 1024 + 512 + lane * 8);
        const float zv = zinv_lds[jt * 16 + l15];
        #pragma unroll
        for (int it = 0; it < 4; ++it) {
            f32x4 e = {0.f, 0.f, 0.f, 0.f};
            e = MFMA_BF16(A0[it], B0, e);
            e = MFMA_BF16(A1[it], B1, e);
            sacc[it][0] += EXP2(e[0]) * zv;
            sacc[it][1] += EXP2(e[1]) * zv;
            sacc[it][2] += EXP2(e[2]) * zv;
            sacc[it][3] += EXP2(e[3]) * zv;
        }
    }
    // phase-1 epilogue: s per row -> s_lds
    #pragma unroll
    for (int it = 0; it < 4; ++it) {
        #pragma unroll
        for (int r = 0; r < 4; ++r) {
            float v = sacc[it][r];
            v += __shfl_xor(v, 1);
            v += __shfl_xor(v, 2);
            v += __shfl_xor(v, 4);
            v += __shfl_xor(v, 8);
            if (l15 == 0) s_lds[w * 64 + it * 16 + lg * 4 + r] = v;
        }
    }
    __syncthreads();

    // phase 2: gap partial = sum_i s_i * (K_EINV*pr_e[i,c] + pd[i,c])
    float g0[8] = {}, g1[8] = {};
    #pragma unroll 2
    for (int it = 0; it < 4; ++it) {
        const bf16* p = pdb + (size_t)(ic * 32 + w * 4 + it) * 1024 + lane * 8;
        bf16x8 PD0 = *(const bf16x8*)p;
        bf16x8 PD1 = *(const bf16x8*)(p + 512);
        const float sv = s_lds[w * 64 + it * 16 + l15];
        #pragma unroll
        for (int k = 0; k < 8; ++k) {
            g0[k] += sv * (K_EINV * (float)A0[it][k] + (float)PD0[k]);
            g1[k] += sv * (K_EINV * (float)A1[it][k] + (float)PD1[k]);
        }
    }
    #pragma unroll 2
    for (int k = 0; k < 8; ++k) {
        float v0 = g0[k], v1 = g1[k];
        v0 += __shfl_xor(v0, 1);
        v0 += __shfl_xor(v0, 2);
        v0 += __shfl_xor(v0, 4);
        v0 += __shfl_xor(v0, 8);
        v1 += __shfl_xor(v1, 1);
        v1 += __shfl_xor(v1, 2);
        v1 += __shfl_xor(v1, 4);
        v1 += __shfl_xor(v1, 8);
        if (l15 == 0) {
            gred[w][lg * 8 + k] = v0;
            gred[w][32 + lg * 8 + k] = v1;
        }
    }
    __syncthreads();
    if (tid < 64) {
        float s = 0.f;
        #pragma unroll
        for (int k = 0; k < 8; ++k) s += gred[k][tid];
        gapPart[((size_t)b * 64 + jc * 8 + ic) * 64 + tid] = s;
        __threadfence();
        int old = atomicAdd(counter, 1);
        if (old == 256 * 64 - 1) winflag = 1;
    }
    __syncthreads();

    // ================= last block: MLP gate ==================
    if (winflag) {
        __threadfence();
        const int wb = w >> 1, half = w & 1;
        float acc2 = 0.f;
        const float* gp = gapPart + ((size_t)wb * 64 + half * 32) * 64 + lane;
        #pragma unroll 4
        for (int r = 0; r < 32; ++r) acc2 += gp[r * 64];
        const float* rp = rgbdPart + ((size_t)wb * 128 + half * 64) * 64 + lane;
        #pragma unroll 4
        for (int r = 0; r < 64; ++r) acc2 += rp[r * 64];
        gred[w][lane] = acc2;
        __syncthreads();
        if (tid < 256) {
            const int b4 = tid >> 6, c = tid & 63;
            gv4[b4][c] = (gred[2 * b4][c] + gred[2 * b4 + 1][c]) * (1.f / 4096.f);
        }
        __syncthreads();
        if (tid < 96) {
            const int b4 = tid / 24, o = tid % 24;
            float a = 0.f;
            #pragma unroll
            for (int cc = 0; cc < 64; ++cc) a += mlp1_w[o * 64 + cc] * gv4[b4][cc];
            float sc = bn2_g[o] * rsqrtf(bn2_v[o] + 1e-5f);
            a = a * sc + bn2_b[o] - bn2_m[o] * sc;
            h4[b4][o] = a > 0.f ? a : 0.f;
        }
        __syncthreads();
        if (tid < 256) {
            const int b4 = tid >> 6, c = tid & 63;
            float u = 0.f;
            #pragma unroll
            for (int o = 0; o < 24; ++o) u += mlp2_w[c * 24 + o] * h4[b4][o];
            float sc = bn3_g[c] * rsqrtf(bn3_v[c] + 1e-5f);
            u = u * sc + bn3_b[c] - bn3_m[c] * sc;
            out[b4 * 64 + c] = 1.f / (1.f + __expf(-u));
        }
    }
}

// ---------------------------------------------------------------------------
extern "C" void kernel_launch(void* const* d_in, const int* in_sizes, int n_in,
                              void* d_out, int out_size, void* d_ws, size_t ws_size,
                              hipStream_t stream)
{
    const float* rgb    = (const float*)d_in[0];
    const float* dep    = (const float*)d_in[1];
    const float* conv_w = (const float*)d_in[2];
    const float* bn1_g  = (const float*)d_in[3];
    const float* bn1_b  = (const float*)d_in[4];
    const float* bn1_m  = (const float*)d_in[5];
    const float* bn1_v  = (const float*)d_in[6];
    const float* rgb_w  = (const float*)d_in[7];
    const float* dep_w  = (const float*)d_in[8];
    const float* mlp1_w = (const float*)d_in[9];
    const float* bn2_g  = (const float*)d_in[10];
    const float* bn2_b  = (const float*)d_in[11];
    const float* bn2_m  = (const float*)d_in[12];
    const float* bn2_v  = (const float*)d_in[13];
    const float* mlp2_w = (const float*)d_in[14];
    const float* bn3_g  = (const float*)d_in[15];
    const float* bn3_b  = (const float*)d_in[16];
    const float* bn3_m  = (const float*)d_in[17];
    const float* bn3_v  = (const float*)d_in[18];

    char* ws = (char*)d_ws;
    bf16*  prF      = (bf16*)(ws);                                  // 2 MB
    bf16*  pdF      = (bf16*)(ws + (2u << 20));                     // 2 MB
    float* Zpart    = (float*)(ws + (4u << 20));                    // 512 KB
    float* rgbdPart = (float*)(ws + (4u << 20) + (512u << 10));     // 128 KB
    float* gapPart  = (float*)(ws + (4u << 20) + (640u << 10));     // 64 KB
    int*   counter  = (int*)  (ws + (4u << 20) + (704u << 10));     // 4 B

    k_front<<<512, 512, 0, stream>>>(rgb, dep, conv_w,
                                     bn1_g, bn1_b, bn1_m, bn1_v,
                                     rgb_w, dep_w,
                                     prF, pdF, rgbdPart, counter);
    k_z<<<256, 512, 0, stream>>>(prF, pdF, Zpart);
    k_s<<<256, 512, 0, stream>>>(prF, pdF, Zpart, gapPart, rgbdPart, counter,
                                 mlp1_w, bn2_g, bn2_b, bn2_m, bn2_v,
                                 mlp2_w, bn3_g, bn3_b, bn3_m, bn3_v,
                                 (float*)d_out);
}